// Round 8
// baseline (86.735 us; speedup 1.0000x reference)
//
#include <hip/hip_runtime.h>

// QuantizedConv2d int8 3x3, N=64, Cin=Cout=128, 56x56, pad=1 (value = input zp),
// int32 accum, per-channel requant. Harness widens integer arrays to int32
// (inputs AND output buffer).
//
// R8: conv K-loop restructured — B (weights) now loaded global->REGISTERS
// per-lane (L1/L2-hot, 3-deep register pipeline, issued 2 steps ahead), no
// B-LDS, no K-loop barriers. x-tile staging, swizzle algebra, MFMA mapping,
// epilogue are byte-identical to the verified R7. repack_x / pack_w2 unchanged.

#define CIN  128
#define COUT 128
#define HW   56
#define NPIX (HW * HW)
#define ROWS  4
#define QCOLS 58
#define XROW  (QCOLS * CIN)          // 7424 B per padded row
#define XP_OFF 147456                // xp starts after wp2 in d_ws
#define XP_ROWS (64 * QCOLS)         // 3712
#define STEPS 36                     // 9 taps x 4 ci-blocks, 4KB of B each

typedef int v4i  __attribute__((ext_vector_type(4)));
typedef int v16i __attribute__((ext_vector_type(16)));

__device__ __forceinline__ void gl16(const void* g, void* l) {
    __builtin_amdgcn_global_load_lds(
        (const __attribute__((address_space(1))) unsigned*)g,
        (__attribute__((address_space(3))) unsigned*)l, 16, 0, 0);
}

// ---- pack weights, swizzled (unchanged, verified) ----
// step = t*4+cb; in-chunk granule g = cout*2+(dw>>2); gs = g ^ ((g>>3)&7);
// chunk dword = gs*4 + (dw&3). byte b of dword dw -> ci = cb*32+dw*4+b, tap t.
__global__ __launch_bounds__(256) void pack_w2(const int* __restrict__ w_g,
                                               unsigned* __restrict__ wp2) {
    int i = blockIdx.x * 256 + threadIdx.x;
    if (i >= 36 * 128 * 8) return;
    int dw   = i & 7;
    int cout = (i >> 3) & 127;
    int step = i >> 10;
    int t  = step >> 2;
    int cb = step & 3;
    unsigned d = 0;
#pragma unroll
    for (int b = 0; b < 4; ++b) {
        int ci = cb * 32 + dw * 4 + b;
        int v = w_g[(cout * CIN + ci) * 9 + t];
        d |= (unsigned)(v & 0xFF) << (8 * b);
    }
    int g  = (cout << 1) | (dw >> 2);
    int gs = g ^ ((g >> 3) & 7);
    wp2[step * 1024 + gs * 4 + (dw & 3)] = d;
}

// ---- repack x: LDS transpose (unchanged, verified) ----
#define LSTR 57
__global__ __launch_bounds__(256) void repack_x(const int* __restrict__ x_g,
                                                unsigned char* __restrict__ xp,
                                                const int* __restrict__ zp_in_p) {
    __shared__ int lx[CIN * LSTR];
    const int blk = blockIdx.x;          // n*58 + hp
    const int n  = blk / QCOLS;
    const int hp = blk % QCOLS;
    const int tid = threadIdx.x;
    const unsigned zpd = (unsigned)((*zp_in_p) & 0xFF) * 0x01010101u;
    unsigned* row = (unsigned*)(xp + (size_t)blk * XROW);

    if (hp == 0 || hp == QCOLS - 1) {
#pragma unroll
        for (int it = 0; it < 8; ++it) {
            int d = it * 256 + tid;
            if (d < QCOLS * 32) row[d] = zpd;
        }
        return;
    }
    const int h = hp - 1;
    const int* xrow = x_g + (n * CIN * HW + h) * HW;
#pragma unroll
    for (int it = 0; it < 7; ++it) {
        int idx = it * 256 + tid;
        int ci  = idx / 14;
        int w4  = (idx - ci * 14) * 4;
        v4i L = *(const v4i*)(xrow + ci * NPIX + w4);
        int* ld = &lx[ci * LSTR + w4];
        ld[0] = L[0]; ld[1] = L[1]; ld[2] = L[2]; ld[3] = L[3];
    }
    __syncthreads();
#pragma unroll
    for (int it = 0; it < 8; ++it) {
        int d = it * 256 + tid;
        if (d < QCOLS * 32) {
            int wp  = d >> 5;
            int ci4 = d & 31;
            unsigned v = zpd;
            if (wp >= 1 && wp <= HW) {
                const int* lb = &lx[ci4 * 4 * LSTR + (wp - 1)];
                v = (unsigned)(lb[0] & 0xFF) |
                    ((unsigned)(lb[LSTR] & 0xFF) << 8) |
                    ((unsigned)(lb[2 * LSTR] & 0xFF) << 16) |
                    ((unsigned)(lb[3 * LSTR] & 0xFF) << 24);
            }
            row[d] = v;
        }
    }
}

// ---- conv: B in registers, barrier-free K-loop ----
__global__ __launch_bounds__(256, 2) void conv_mfma(
    const unsigned char* __restrict__ xp, const unsigned char* __restrict__ wp2b,
    const int* __restrict__ bias, const float* __restrict__ in_s,
    const float* __restrict__ w_s, const float* __restrict__ out_s,
    const int* __restrict__ zp_out_p, int* __restrict__ out) {
    __shared__ unsigned char xsb[45056];     // 44 x 1024B (348 rows used)
    __shared__ float scs[COUT];
    __shared__ int   bis[COUT];

    const int n   = blockIdx.x / 14;
    const int ho0 = (blockIdx.x % 14) * ROWS;
    const int tid    = threadIdx.x;
    const int lane   = tid & 63;
    const int wave   = tid >> 6;
    const int lane31 = lane & 31;
    const int hi     = lane >> 5;
    const int hi4    = hi * 4;

    if (tid < COUT) {
        scs[tid] = ((*in_s) / (*out_s)) * w_s[tid];
        bis[tid] = bias[tid];
    }

    // ---- stage x window: 6 padded rows = 44544 contiguous bytes ----
    const unsigned char* win = xp + (size_t)(n * QCOLS + ho0) * XROW;
    const int qrel = lane >> 3;
    const int lof  = (qrel * 8 + ((lane & 7) ^ qrel)) * 16;
    for (int i = wave; i < 44; i += 4) {
        int off = i * 1024 + lof;
        if (i == 43 && qrel >= 4) off = 0;           // rows 348+ unused
        gl16(win + off, xsb + i * 1024);
    }
    __syncthreads();

    const unsigned* xs = (const unsigned*)xsb;
    int qb0, qb1;
    {
        int px0 = wave * 64 + lane31;
        int px1 = wave * 64 + 32 + lane31;
        if (px1 > ROWS * HW - 1) px1 = ROWS * HW - 1;   // wave3 second tile pad
        qb0 = (px0 / HW) * QCOLS + (px0 % HW);
        qb1 = (px1 / HW) * QCOLS + (px1 % HW);
    }
    // per-lane B base pointers (swizzled granule offsets, verified pairing)
    const unsigned char *bpA, *bpB, *bpC, *bpD;
    {
        int g0 = 0 * 64 + lane31 * 2 + hi;
        int g1 = 1 * 64 + lane31 * 2 + hi;
        int g2 = 2 * 64 + lane31 * 2 + hi;
        int g3 = 3 * 64 + lane31 * 2 + hi;
        bpA = wp2b + (g0 ^ ((g0 >> 3) & 7)) * 16;
        bpB = wp2b + (g1 ^ ((g1 >> 3) & 7)) * 16;
        bpC = wp2b + (g2 ^ ((g2 >> 3) & 7)) * 16;
        bpD = wp2b + (g3 ^ ((g3 >> 3) & 7)) * 16;
    }

    v16i acc[2][4];
#pragma unroll
    for (int i = 0; i < 2; ++i)
#pragma unroll
        for (int j = 0; j < 4; ++j) acc[i][j] = (v16i)0;

    v4i c0[4], c1[4], c2[4];
#define LOADB(DST, S)                                                        \
    {                                                                        \
        DST[0] = *(const v4i*)(bpA + (S) * 4096);                            \
        DST[1] = *(const v4i*)(bpB + (S) * 4096);                            \
        DST[2] = *(const v4i*)(bpC + (S) * 4096);                            \
        DST[3] = *(const v4i*)(bpD + (S) * 4096);                            \
    }
#define BODY(S, CUR, NX2)                                                    \
    {                                                                        \
        if ((S) + 2 < STEPS) LOADB(NX2, (S) + 2);                            \
        const int t2 = (S) >> 2, cb = (S) & 3;                               \
        const int kr = (t2 * 11) >> 5;                                       \
        const int dq = kr * QCOLS + (t2 - 3 * kr);                           \
        const int q0 = qb0 + dq, q1 = qb1 + dq;                              \
        v4i a0 = *(const v4i*)&xs[q0 * 32 + ((cb * 8 + hi4) ^ ((q0 & 7) << 2))]; \
        v4i a1 = *(const v4i*)&xs[q1 * 32 + ((cb * 8 + hi4) ^ ((q1 & 7) << 2))]; \
        acc[0][0] = __builtin_amdgcn_mfma_i32_32x32x32_i8(CUR[0], a0, acc[0][0], 0, 0, 0); \
        acc[0][1] = __builtin_amdgcn_mfma_i32_32x32x32_i8(CUR[1], a0, acc[0][1], 0, 0, 0); \
        acc[0][2] = __builtin_amdgcn_mfma_i32_32x32x32_i8(CUR[2], a0, acc[0][2], 0, 0, 0); \
        acc[0][3] = __builtin_amdgcn_mfma_i32_32x32x32_i8(CUR[3], a0, acc[0][3], 0, 0, 0); \
        acc[1][0] = __builtin_amdgcn_mfma_i32_32x32x32_i8(CUR[0], a1, acc[1][0], 0, 0, 0); \
        acc[1][1] = __builtin_amdgcn_mfma_i32_32x32x32_i8(CUR[1], a1, acc[1][1], 0, 0, 0); \
        acc[1][2] = __builtin_amdgcn_mfma_i32_32x32x32_i8(CUR[2], a1, acc[1][2], 0, 0, 0); \
        acc[1][3] = __builtin_amdgcn_mfma_i32_32x32x32_i8(CUR[3], a1, acc[1][3], 0, 0, 0); \
    }

    LOADB(c0, 0);
    LOADB(c1, 1);
#pragma unroll 1
    for (int uu = 0; uu < 12; ++uu) {
        const int s = uu * 3;
        BODY(s + 0, c0, c2);
        BODY(s + 1, c1, c0);
        BODY(s + 2, c2, c1);
    }
#undef BODY
#undef LOADB

    // ---- epilogue: D row = cout-in-tile = (reg&3)+8*(reg>>2)+hi4, col = px ----
    const float zpo = (float)(*zp_out_p);
#pragma unroll
    for (int i = 0; i < 2; ++i) {
        const int px = wave * 64 + i * 32 + lane31;
        if (px < ROWS * HW) {
            int* ob = out + n * COUT * NPIX + ho0 * HW + px;
#pragma unroll
            for (int nt = 0; nt < 4; ++nt) {
#pragma unroll
                for (int reg = 0; reg < 16; ++reg) {
                    int co = nt * 32 + (reg & 3) + 8 * (reg >> 2) + hi4;
                    float f = fmaf((float)(acc[i][nt][reg] + bis[co]), scs[co], zpo);
                    f = rintf(f);
                    f = fminf(fmaxf(f, -128.0f), 127.0f);
                    ob[co * NPIX] = (int)f;
                }
            }
        }
    }
}

extern "C" void kernel_launch(void* const* d_in, const int* in_sizes, int n_in,
                              void* d_out, int out_size, void* d_ws, size_t ws_size,
                              hipStream_t stream) {
    const int* x_g      = (const int*)d_in[0];
    const int* w_g      = (const int*)d_in[1];
    const int* bias     = (const int*)d_in[2];
    const float* in_s   = (const float*)d_in[3];
    const float* w_s    = (const float*)d_in[4];
    const float* out_s  = (const float*)d_in[5];
    const int* zp_in_p  = (const int*)d_in[6];
    const int* zp_out_p = (const int*)d_in[7];
    int* outp = (int*)d_out;
    unsigned* wp2 = (unsigned*)d_ws;                           // 147456 B
    unsigned char* xpp = (unsigned char*)d_ws + XP_OFF;        // 27,557,888 B

    pack_w2<<<(36 * 128 * 8 + 255) / 256, 256, 0, stream>>>(w_g, wp2);
    repack_x<<<XP_ROWS, 256, 0, stream>>>(x_g, xpp, zp_in_p);

    const int nblocks = 64 * (HW / ROWS);   // 896
    conv_mfma<<<nblocks, 256, 0, stream>>>(xpp, (const unsigned char*)wp2, bias,
                                           in_s, w_s, out_s, zp_out_p, outp);
}